// Round 11
// baseline (255.054 us; speedup 1.0000x reference)
//
#include <hip/hip_runtime.h>
#include <cstdint>

#define S_LEN 2048
#define D_MODEL 512
#define H_NUM 8
#define DH 64
#define LOG2E 1.4426950408889634f

typedef __attribute__((ext_vector_type(8))) short bf16x8;
typedef __attribute__((ext_vector_type(8))) unsigned short u16x8;
typedef __attribute__((ext_vector_type(4))) float f32x4;

__device__ inline unsigned short f2bf(float x) {
    unsigned int u = __builtin_bit_cast(unsigned int, x);
    u += 0x7fffu + ((u >> 16) & 1u);          // round-to-nearest-even
    return (unsigned short)(u >> 16);
}
__device__ inline float bf2f(unsigned short u) {
    return __builtin_bit_cast(float, (unsigned int)u << 16);
}
// pack two f32 -> (bf16(b)<<16)|bf16(a), round-half-up (1 ULP bias negligible)
__device__ inline unsigned pack_bf2(float a, float b) {
    unsigned ua = __builtin_bit_cast(unsigned, a) + 0x8000u;
    unsigned ub = __builtin_bit_cast(unsigned, b) + 0x8000u;
    return __builtin_amdgcn_perm(ub, ua, 0x07060302);
}

// async global->LDS DMA, 16B per lane; HW writes lane i's 16B to lds + 16*i.
__device__ inline void async_ld16(const unsigned short* g, unsigned short* l) {
    __builtin_amdgcn_global_load_lds(
        (const __attribute__((address_space(1))) unsigned int*)(const unsigned int*)g,
        (__attribute__((address_space(3))) unsigned int*)(unsigned int*)l,
        16, 0, 0);
}

// ---------------- Kernel 0: prep — convert X to bf16; transpose W's to bf16 [n][k] ----------------
__global__ __launch_bounds__(256) void prep(
    const float* __restrict__ X, const float* __restrict__ Wqkv,
    const float* __restrict__ Wo,
    unsigned short* __restrict__ Xb, unsigned short* __restrict__ WqkvT,
    unsigned short* __restrict__ WoT)
{
    __shared__ float tile[32][36];
    const int blk = blockIdx.x;
    const int tid = threadIdx.x;
    if (blk < 1024) {
        const int base = blk * 4096 + tid * 16;
        #pragma unroll
        for (int i = 0; i < 4; ++i) {
            float4 v = *(const float4*)(X + base + i * 4);
            ushort4 o;
            o.x = f2bf(v.x); o.y = f2bf(v.y); o.z = f2bf(v.z); o.w = f2bf(v.w);
            *(ushort4*)(Xb + base + i * 4) = o;
        }
        return;
    }
    const float* src; unsigned short* dst; int N, t;
    if (blk < 1792) { src = Wqkv; dst = WqkvT; N = 1536; t = blk - 1024; }
    else            { src = Wo;   dst = WoT;   N = 512;  t = blk - 1792; }
    const int tnx = N / 32;
    const int bx = t % tnx;
    const int by = t / tnx;
    const int row = tid >> 3;
    const int c4  = (tid & 7) * 4;
    *(float4*)&tile[row][c4] = *(const float4*)(src + (size_t)(by * 32 + row) * N + bx * 32 + c4);
    __syncthreads();
    ushort4 o;
    o.x = f2bf(tile[c4 + 0][row]);
    o.y = f2bf(tile[c4 + 1][row]);
    o.z = f2bf(tile[c4 + 2][row]);
    o.w = f2bf(tile[c4 + 3][row]);
    *(ushort4*)(dst + (size_t)(bx * 32 + row) * 512 + by * 32 + c4) = o;
}

// ---------------- Kernel A: QKV projection, bf16 MFMA, BK=64 ----------------
// Q is PRE-SCALED by log2(e) so attention softmax can use raw exp2.
__global__ __launch_bounds__(256) void qkv_mfma(
    const unsigned short* __restrict__ Xb, const unsigned short* __restrict__ WT,
    const float* __restrict__ bias,
    unsigned short* __restrict__ Q, unsigned short* __restrict__ K,
    unsigned short* __restrict__ Vt)
{
    __shared__ unsigned short sA[128 * 64];
    __shared__ unsigned short sB[128 * 64];
    const int tid  = threadIdx.x;
    const int w    = tid >> 6;
    const int lane = tid & 63;
    const int l16  = lane & 15;
    const int quad = lane >> 4;
    const int wm = w >> 1, wn = w & 1;
    const int n0 = blockIdx.x * 128;
    const int m0 = blockIdx.y * 128;

    const unsigned short* gA[4]; const unsigned short* gB[4];
    unsigned short *lA[4], *lB[4];
    #pragma unroll
    for (int j = 0; j < 4; ++j) {
        const int ci = tid + j * 256;
        const int row = ci >> 3;
        const int col = ((ci & 7) ^ (row & 7)) * 8;
        gA[j] = Xb + (size_t)(m0 + row) * 512 + col;
        gB[j] = WT + (size_t)(n0 + row) * 512 + col;
        lA[j] = sA + ci * 8 - lane * 8;
        lB[j] = sB + ci * 8 - lane * 8;
    }

    f32x4 acc[4][4] = {};
    for (int k0 = 0; k0 < 512; k0 += 64) {
        __syncthreads();
        #pragma unroll
        for (int j = 0; j < 4; ++j) {
            async_ld16(gA[j] + k0, lA[j]);
            async_ld16(gB[j] + k0, lB[j]);
        }
        __syncthreads();
        bf16x8 a[4][2], bfr[4][2];
        #pragma unroll
        for (int mi = 0; mi < 4; ++mi) {
            const int row = wm * 64 + mi * 16 + l16;
            a[mi][0] = *(const bf16x8*)&sA[row * 64 + ((quad       ^ (row & 7)) * 8)];
            a[mi][1] = *(const bf16x8*)&sA[row * 64 + (((4 + quad) ^ (row & 7)) * 8)];
        }
        #pragma unroll
        for (int ni = 0; ni < 4; ++ni) {
            const int row = wn * 64 + ni * 16 + l16;
            bfr[ni][0] = *(const bf16x8*)&sB[row * 64 + ((quad       ^ (row & 7)) * 8)];
            bfr[ni][1] = *(const bf16x8*)&sB[row * 64 + (((4 + quad) ^ (row & 7)) * 8)];
        }
        #pragma unroll
        for (int mi = 0; mi < 4; ++mi)
            #pragma unroll
            for (int ni = 0; ni < 4; ++ni) {
                acc[mi][ni] = __builtin_amdgcn_mfma_f32_16x16x32_bf16(a[mi][0], bfr[ni][0], acc[mi][ni], 0, 0, 0);
                acc[mi][ni] = __builtin_amdgcn_mfma_f32_16x16x32_bf16(a[mi][1], bfr[ni][1], acc[mi][ni], 0, 0, 0);
            }
    }

    const int which = n0 >> 9;
    const int h = ((n0 & 511) >> 6) + wn;
    const int b = m0 >> 11;
    const int sbase = (m0 & 2047) + wm * 64;
    float bv[4];
    #pragma unroll
    for (int ni = 0; ni < 4; ++ni) bv[ni] = bias[n0 + wn * 64 + ni * 16 + l16];
    if (which == 2) {
        #pragma unroll
        for (int ni = 0; ni < 4; ++ni) {
            const int dh = ni * 16 + l16;
            unsigned short* vp = Vt + ((size_t)(b * H_NUM + h) * DH + dh) * S_LEN;
            #pragma unroll
            for (int mi = 0; mi < 4; ++mi) {
                const int s0 = sbase + mi * 16 + quad * 4;
                ushort4 o;
                o.x = f2bf(acc[mi][ni][0] + bv[ni]);
                o.y = f2bf(acc[mi][ni][1] + bv[ni]);
                o.z = f2bf(acc[mi][ni][2] + bv[ni]);
                o.w = f2bf(acc[mi][ni][3] + bv[ni]);
                *(ushort4*)(vp + s0) = o;
            }
        }
    } else {
        const float qs = (which == 0) ? LOG2E : 1.0f;   // Q pre-scaled for exp2 softmax
        unsigned short* dst = (which == 0) ? Q : K;
        dst += (size_t)(b * H_NUM + h) * S_LEN * DH;
        #pragma unroll
        for (int mi = 0; mi < 4; ++mi)
            #pragma unroll
            for (int r = 0; r < 4; ++r) {
                const int s = sbase + mi * 16 + quad * 4 + r;
                #pragma unroll
                for (int ni = 0; ni < 4; ++ni)
                    dst[(size_t)s * DH + ni * 16 + l16] = f2bf((acc[mi][ni][r] + bv[ni]) * qs);
            }
    }
}

// ---------------- Kernel B: flash attention — kt-split + permuted-K register-direct P ----------------
// Grid (16 qt, 32 bh, 2 z). Block: 128 Q rows, K-tiles z*16..z*16+15.
// 4 waves = 2 qg x 2 kg. Wave (qg,kg): q-rows qg*64 + t*16 + [0,16), kpos kg*32+[0,32).
// S^T QK with PERMUTED K rows: c0's m-block loads kpos π(m)=8(m>>2)+(m&3), c1 loads π+4.
// Then lane (l16,quad) exits QK holding kpos {8q..8q+7} for qrow=l16 — exactly the
// PV A-fragment layout. P: C-regs -> pack_bf2 -> PV operand. No LDS, no shuffles.
// Additive softmax partials (O bf16, l f32) written per z; attn_reduce merges.
__global__ __launch_bounds__(256, 3) void attn_mfma(
    const unsigned short* __restrict__ Q, const unsigned short* __restrict__ K,
    const unsigned short* __restrict__ Vt, const int* __restrict__ mask,
    unsigned short* __restrict__ Opart, float* __restrict__ lpart)
{
    __shared__ __align__(16) char smem[36864];
    unsigned short* sK  = (unsigned short*)smem;            // [2][4096] swizzled
    unsigned short* sVt = (unsigned short*)(smem + 16384);  // [2][4096] swizzled
    float* smbt = (float*)(smem + 32768);                   // [2][64]
    // epilogue aliases (after post-loop barrier):
    float* red  = (float*)smem;                             // [128][68]
    float* lred = (float*)(smem + 34816);                   // [2][128]

    const int tid  = threadIdx.x;
    const int w    = tid >> 6;
    const int lane = tid & 63;
    const int l16  = lane & 15;
    const int quad = lane >> 4;
    const int qg = w >> 1;           // q-group: rows qg*64..+63
    const int kg = w & 1;            // k-group: kpos kg*32..+31 of each 64-tile
    const int qt = blockIdx.x;       // 0..15
    const int bh = blockIdx.y;       // 0..31
    const int z  = blockIdx.z;       // 0..1 — K-tile half
    const int b  = bh >> 3;
    const int h  = bh & 7;
    const size_t kbase = (size_t)bh * S_LEN * DH;
    const size_t vbase = (size_t)bh * DH * S_LEN;
    const int kt0 = z * 16;

    // Q fragments direct from global (B-operand: n=qrow=l16, k=quad*8+j)
    bf16x8 qf[4][2];
    {
        const unsigned short* qp = Q + kbase + (size_t)(qt * 128 + qg * 64 + l16) * DH + quad * 8;
        #pragma unroll
        for (int t = 0; t < 4; ++t) {
            qf[t][0] = *(const bf16x8*)(qp + t * 16 * DH);
            qf[t][1] = *(const bf16x8*)(qp + t * 16 * DH + 32);
        }
    }

    // DMA chunk geometry (512 chunks per 8KB tile; 8 chunks/row, XOR row&7)
    const int ci0 = w * 128 + lane;
    const int ci1 = ci0 + 64;
    const int r0_ = ci0 >> 3, c0_ = ((ci0 & 7) ^ (r0_ & 7)) * 8;
    const int r1_ = ci1 >> 3, c1_ = ((ci1 & 7) ^ (r1_ & 7)) * 8;
    const int kOff0 = r0_ * 64 + c0_;
    const int kOff1 = r1_ * 64 + c1_;
    const int vOff0 = r0_ * S_LEN + c0_;
    const int vOff1 = r1_ * S_LEN + c1_;
    const int lds0 = ci0 * 8 - lane * 8;
    const int lds1 = ci1 * 8 - lane * 8;

    f32x4 O[4][4] = {};      // [t][db]
    float lacc[4] = {};      // per-lane l partial (qrow = l16 of tile t)

    // permuted K row (π for c0; c1 adds 4): kpos = 8*(l16>>2) + (l16&3)
    const int prow = (l16 >> 2) * 8 + (l16 & 3);

    // prologue: prefetch tile kt0 into buffer 0
    {
        const unsigned short* gK = K  + kbase + (size_t)kt0 * 64 * DH;
        const unsigned short* gV = Vt + vbase + kt0 * 64;
        async_ld16(gK + kOff0, sK + lds0);
        async_ld16(gK + kOff1, sK + lds1);
        async_ld16(gV + vOff0, sVt + lds0);
        async_ld16(gV + vOff1, sVt + lds1);
        if (tid < 64) smbt[tid] = mask[b * S_LEN + kt0 * 64 + tid] ? 0.f : -1e30f;
    }

    for (int kt = 0; kt < 16; ++kt) {
        const int cur = kt & 1, nxt = cur ^ 1;
        __syncthreads();   // drains DMA(kt), orders smbt, fences buffer reuse
        if (kt + 1 < 16) {
            const unsigned short* gK = K  + kbase + (size_t)(kt0 + kt + 1) * 64 * DH;
            const unsigned short* gV = Vt + vbase + (kt0 + kt + 1) * 64;
            async_ld16(gK + kOff0, sK + nxt * 4096 + lds0);
            async_ld16(gK + kOff1, sK + nxt * 4096 + lds1);
            async_ld16(gV + vOff0, sVt + nxt * 4096 + lds0);
            async_ld16(gV + vOff1, sVt + nxt * 4096 + lds1);
            if (tid < 64) smbt[nxt * 64 + tid] = mask[b * S_LEN + (kt0 + kt + 1) * 64 + tid] ? 0.f : -1e30f;
        }
        const unsigned short* sKc = sK  + cur * 4096;
        const unsigned short* sVc = sVt + cur * 4096;

        // K fragments (A-operand, m=kpos) with π permutation
        bf16x8 kb[2][2];
        #pragma unroll
        for (int kpb = 0; kpb < 2; ++kpb) {
            const int row = kg * 32 + prow + kpb * 4;   // kpb=0 -> c0 rows, 1 -> c1 rows
            const int x = row & 7;
            kb[kpb][0] = *(const bf16x8*)&sKc[row * 64 + ((quad       ^ x) * 8)];
            kb[kpb][1] = *(const bf16x8*)&sKc[row * 64 + (((4 + quad) ^ x) * 8)];
        }
        // mask bias follows the permutation: c0 reg r <-> kpos 8q+r, c1 <-> 8q+4+r
        float4 mb0 = *(const float4*)&smbt[cur * 64 + kg * 32 + quad * 8];
        float4 mb1 = *(const float4*)&smbt[cur * 64 + kg * 32 + quad * 8 + 4];

        // V fragments (B-operand, n=dh, k = this wave's 32 kpos)
        bf16x8 vb[4];
        #pragma unroll
        for (int db = 0; db < 4; ++db) {
            const int row = db * 16 + l16;
            const int x = row & 7;
            vb[db] = *(const bf16x8*)&sVc[row * 64 + (((kg * 4 + quad) ^ x) * 8)];
        }

        #pragma unroll
        for (int t = 0; t < 4; ++t) {
            f32x4 c0 = {0,0,0,0}, c1 = {0,0,0,0};
            c0 = __builtin_amdgcn_mfma_f32_16x16x32_bf16(kb[0][0], qf[t][0], c0, 0, 0, 0);
            c0 = __builtin_amdgcn_mfma_f32_16x16x32_bf16(kb[0][1], qf[t][1], c0, 0, 0, 0);
            c1 = __builtin_amdgcn_mfma_f32_16x16x32_bf16(kb[1][0], qf[t][0], c1, 0, 0, 0);
            c1 = __builtin_amdgcn_mfma_f32_16x16x32_bf16(kb[1][1], qf[t][1], c1, 0, 0, 0);

            // p = exp2(score + maskbias); lane holds kpos 8q+0..7 for qrow=l16
            const float p0 = __builtin_amdgcn_exp2f(c0[0] + mb0.x);
            const float p1 = __builtin_amdgcn_exp2f(c0[1] + mb0.y);
            const float p2 = __builtin_amdgcn_exp2f(c0[2] + mb0.z);
            const float p3 = __builtin_amdgcn_exp2f(c0[3] + mb0.w);
            const float p4 = __builtin_amdgcn_exp2f(c1[0] + mb1.x);
            const float p5 = __builtin_amdgcn_exp2f(c1[1] + mb1.y);
            const float p6 = __builtin_amdgcn_exp2f(c1[2] + mb1.z);
            const float p7 = __builtin_amdgcn_exp2f(c1[3] + mb1.w);
            lacc[t] += ((p0 + p1) + (p2 + p3)) + ((p4 + p5) + (p6 + p7));

            uint4 paw;
            paw.x = pack_bf2(p0, p1);   // kpos 8q+0,1
            paw.y = pack_bf2(p2, p3);   // kpos 8q+2,3
            paw.z = pack_bf2(p4, p5);   // kpos 8q+4,5
            paw.w = pack_bf2(p6, p7);   // kpos 8q+6,7
            const bf16x8 pa = __builtin_bit_cast(bf16x8, paw);
            #pragma unroll
            for (int db = 0; db < 4; ++db)
                O[t][db] = __builtin_amdgcn_mfma_f32_16x16x32_bf16(pa, vb[db], O[t][db], 0, 0, 0);
        }
    }

    // ---- epilogue: reduce l over quads; cross-kg reduce via LDS; write partials ----
    #pragma unroll
    for (int t = 0; t < 4; ++t) {
        lacc[t] += __shfl_xor(lacc[t], 16, 64);
        lacc[t] += __shfl_xor(lacc[t], 32, 64);   // all lanes: l(qrow=l16) of tile t
    }
    __syncthreads();                               // main-loop LDS dead; alias as red/lred
    if (quad == 0) {
        #pragma unroll
        for (int t = 0; t < 4; ++t)
            lred[kg * 128 + qg * 64 + t * 16 + l16] = lacc[t];
    }
    if (kg == 1) {
        #pragma unroll
        for (int t = 0; t < 4; ++t)
            #pragma unroll
            for (int db = 0; db < 4; ++db)
                #pragma unroll
                for (int r = 0; r < 4; ++r)
                    red[(size_t)(qg * 64 + t * 16 + quad * 4 + r) * 68 + db * 16 + l16] = O[t][db][r];
    }
    __syncthreads();
    if (kg == 0) {
        const size_t zoff = (size_t)z * 8192;
        #pragma unroll
        for (int t = 0; t < 4; ++t) {
            #pragma unroll
            for (int r = 0; r < 4; ++r) {
                const int lrow = qg * 64 + t * 16 + quad * 4 + r;
                const size_t grow = (size_t)b * S_LEN + qt * 128 + lrow;
                unsigned short* op = Opart + (zoff + grow) * 512 + h * DH + l16;
                op[0]  = f2bf(O[t][0][r] + red[(size_t)lrow * 68 +  0 + l16]);
                op[16] = f2bf(O[t][1][r] + red[(size_t)lrow * 68 + 16 + l16]);
                op[32] = f2bf(O[t][2][r] + red[(size_t)lrow * 68 + 32 + l16]);
                op[48] = f2bf(O[t][3][r] + red[(size_t)lrow * 68 + 48 + l16]);
                if (l16 == 0)
                    lpart[(zoff + grow) * 8 + h] = lred[lrow] + lred[128 + lrow];
            }
        }
    }
}

// ---------------- Kernel B2: merge kt-split partials -> normalized bf16 att ----------------
__global__ __launch_bounds__(256) void attn_reduce(
    const unsigned short* __restrict__ Opart, const float* __restrict__ lpart,
    unsigned short* __restrict__ attb)
{
    const int tid = threadIdx.x;
    const int w = tid >> 6, lane = tid & 63;
    const size_t row = (size_t)blockIdx.x * 4 + w;
    const int c0 = lane * 8;
    const int h = lane >> 3;
    const float l = lpart[row * 8 + h] + lpart[(8192 + row) * 8 + h];
    const float inv = 1.0f / l;
    u16x8 a = *(const u16x8*)(Opart + row * 512 + c0);
    u16x8 bq = *(const u16x8*)(Opart + (size_t)(8192 + row) * 512 + c0);
    u16x8 o;
    #pragma unroll
    for (int j = 0; j < 8; ++j)
        o[j] = f2bf((bf2f(a[j]) + bf2f(bq[j])) * inv);
    *(u16x8*)(attb + row * 512 + c0) = o;
}

// ---------------- Kernel C: out-proj GEMM, bf16 MFMA, BK=64 ----------------
__global__ __launch_bounds__(256) void proj_mfma(
    const unsigned short* __restrict__ attb, const unsigned short* __restrict__ WoT,
    const float* __restrict__ bo, float* __restrict__ xbuf)
{
    __shared__ unsigned short sA[128 * 64];
    __shared__ unsigned short sB[64 * 64];
    const int tid  = threadIdx.x;
    const int w    = tid >> 6;
    const int lane = tid & 63;
    const int l16  = lane & 15;
    const int quad = lane >> 4;
    const int wm = w >> 1, wn = w & 1;
    const int n0 = blockIdx.x * 64;
    const int m0 = blockIdx.y * 128;

    const unsigned short* gA[4]; unsigned short* lA[4];
    const unsigned short* gB[2]; unsigned short* lB[2];
    #pragma unroll
    for (int j = 0; j < 4; ++j) {
        const int ci = tid + j * 256;
        const int row = ci >> 3;
        const int col = ((ci & 7) ^ (row & 7)) * 8;
        gA[j] = attb + (size_t)(m0 + row) * 512 + col;
        lA[j] = sA + ci * 8 - lane * 8;
    }
    #pragma unroll
    for (int j = 0; j < 2; ++j) {
        const int ci = tid + j * 256;
        const int row = ci >> 3;
        const int col = ((ci & 7) ^ (row & 7)) * 8;
        gB[j] = WoT + (size_t)(n0 + row) * 512 + col;
        lB[j] = sB + ci * 8 - lane * 8;
    }

    f32x4 acc[4][2] = {};
    for (int k0 = 0; k0 < 512; k0 += 64) {
        __syncthreads();
        #pragma unroll
        for (int j = 0; j < 4; ++j) async_ld16(gA[j] + k0, lA[j]);
        #pragma unroll
        for (int j = 0; j < 2; ++j) async_ld16(gB[j] + k0, lB[j]);
        __syncthreads();
        bf16x8 a[4][2], bfr[2][2];
        #pragma unroll
        for (int mi = 0; mi < 4; ++mi) {
            const int row = wm * 64 + mi * 16 + l16;
            a[mi][0] = *(const bf16x8*)&sA[row * 64 + ((quad       ^ (row & 7)) * 8)];
            a[mi][1] = *(const bf16x8*)&sA[row * 64 + (((4 + quad) ^ (row & 7)) * 8)];
        }
        #pragma unroll
        for (int ni = 0; ni < 2; ++ni) {
            const int row = wn * 32 + ni * 16 + l16;
            bfr[ni][0] = *(const bf16x8*)&sB[row * 64 + ((quad       ^ (row & 7)) * 8)];
            bfr[ni][1] = *(const bf16x8*)&sB[row * 64 + (((4 + quad) ^ (row & 7)) * 8)];
        }
        #pragma unroll
        for (int mi = 0; mi < 4; ++mi)
            #pragma unroll
            for (int ni = 0; ni < 2; ++ni) {
                acc[mi][ni] = __builtin_amdgcn_mfma_f32_16x16x32_bf16(a[mi][0], bfr[ni][0], acc[mi][ni], 0, 0, 0);
                acc[mi][ni] = __builtin_amdgcn_mfma_f32_16x16x32_bf16(a[mi][1], bfr[ni][1], acc[mi][ni], 0, 0, 0);
            }
    }

    #pragma unroll
    for (int ni = 0; ni < 2; ++ni) {
        const int n = n0 + wn * 32 + ni * 16 + l16;
        const float bv = bo[n];
        #pragma unroll
        for (int mi = 0; mi < 4; ++mi) {
            #pragma unroll
            for (int r = 0; r < 4; ++r) {
                const int m = m0 + wm * 64 + mi * 16 + quad * 4 + r;
                const float resid = bf2f(attb[(size_t)m * 512 + n]);
                xbuf[(size_t)m * 512 + n] = acc[mi][ni][r] + bv + resid;
            }
        }
    }
}

// ---------------- Kernel D: LayerNorm ----------------
__global__ __launch_bounds__(256) void ln_kernel(
    const float* __restrict__ xbuf, const float* __restrict__ gamma,
    const float* __restrict__ beta, float* __restrict__ out)
{
    const int tid = threadIdx.x;
    const int w = tid >> 6, lane = tid & 63;
    const size_t row = (size_t)blockIdx.x * 4 + w;
    const float* xp = xbuf + row * 512 + lane * 8;
    float4 v0 = *(const float4*)xp;
    float4 v1 = *(const float4*)(xp + 4);
    float s  = v0.x + v0.y + v0.z + v0.w + v1.x + v1.y + v1.z + v1.w;
    float sq = v0.x*v0.x + v0.y*v0.y + v0.z*v0.z + v0.w*v0.w
             + v1.x*v1.x + v1.y*v1.y + v1.z*v1.z + v1.w*v1.w;
    #pragma unroll
    for (int off = 1; off < 64; off <<= 1) {
        s  += __shfl_xor(s, off, 64);
        sq += __shfl_xor(sq, off, 64);
    }
    const float mu = s * (1.0f / 512.0f);
    const float var = sq * (1.0f / 512.0f) - mu * mu;
    const float rs = rsqrtf(var + 1e-5f);
    float4 g0 = *(const float4*)(gamma + lane * 8);
    float4 g1 = *(const float4*)(gamma + lane * 8 + 4);
    float4 b0 = *(const float4*)(beta + lane * 8);
    float4 b1 = *(const float4*)(beta + lane * 8 + 4);
    float4 o0, o1;
    o0.x = (v0.x - mu) * rs * g0.x + b0.x;
    o0.y = (v0.y - mu) * rs * g0.y + b0.y;
    o0.z = (v0.z - mu) * rs * g0.z + b0.z;
    o0.w = (v0.w - mu) * rs * g0.w + b0.w;
    o1.x = (v1.x - mu) * rs * g1.x + b1.x;
    o1.y = (v1.y - mu) * rs * g1.y + b1.y;
    o1.z = (v1.z - mu) * rs * g1.z + b1.z;
    o1.w = (v1.w - mu) * rs * g1.w + b1.w;
    float* op = out + row * 512 + lane * 8;
    *(float4*)op = o0;
    *(float4*)(op + 4) = o1;
}

extern "C" void kernel_launch(void* const* d_in, const int* in_sizes, int n_in,
                              void* d_out, int out_size, void* d_ws, size_t ws_size,
                              hipStream_t stream)
{
    (void)in_sizes; (void)n_in; (void)out_size; (void)ws_size;
    const float* X    = (const float*)d_in[0];
    const int*   mask = (const int*)d_in[1];
    const float* Wqkv = (const float*)d_in[2];
    const float* bqkv = (const float*)d_in[3];
    const float* Wo   = (const float*)d_in[4];
    const float* bo   = (const float*)d_in[5];
    const float* gamma= (const float*)d_in[6];
    const float* beta = (const float*)d_in[7];
    float* out = (float*)d_out;

    const size_t NE = (size_t)4 * S_LEN * D_MODEL;      // 4,194,304
    unsigned short* ws16 = (unsigned short*)d_ws;
    unsigned short* Xb     = ws16;                       // NE
    unsigned short* WqkvT  = Xb + NE;                    // 786432
    unsigned short* WoT    = WqkvT + 786432;             // 262144
    unsigned short* Q      = WoT + 262144;               // NE
    unsigned short* K      = Q + NE;                     // NE
    unsigned short* Vt     = K + NE;                     // NE
    unsigned short* attb   = Vt + NE;                    // NE
    float* xbuf = (float*)(attb + NE);                   // NE f32 (16 MB)
    // Opart (bf16, 2 halves x NE = 16 MB) aliases xbuf: dead before proj writes xbuf
    unsigned short* Opart = (unsigned short*)xbuf;
    float* lpart = xbuf + NE;                            // [2][8192][8] f32 = 512 KB

    prep<<<dim3(2048), 256, 0, stream>>>(X, Wqkv, Wo, Xb, WqkvT, WoT);
    qkv_mfma<<<dim3(12, 64), 256, 0, stream>>>(Xb, WqkvT, bqkv, Q, K, Vt);
    attn_mfma<<<dim3(16, 32, 2), 256, 0, stream>>>(Q, K, Vt, mask, Opart, lpart);
    attn_reduce<<<dim3(2048), 256, 0, stream>>>(Opart, lpart, attb);
    proj_mfma<<<dim3(8, 64), 256, 0, stream>>>(attb, WoT, bo, xbuf);
    ln_kernel<<<dim3(2048), 256, 0, stream>>>(xbuf, gamma, beta, out);
}

// Round 12
// 178.992 us; speedup vs baseline: 1.4249x; 1.4249x over previous
//
#include <hip/hip_runtime.h>
#include <cstdint>

#define S_LEN 2048
#define D_MODEL 512
#define H_NUM 8
#define DH 64
#define LOG2E 1.4426950408889634f

typedef __attribute__((ext_vector_type(8))) short bf16x8;
typedef __attribute__((ext_vector_type(8))) unsigned short u16x8;
typedef __attribute__((ext_vector_type(4))) float f32x4;

__device__ inline unsigned short f2bf(float x) {
    unsigned int u = __builtin_bit_cast(unsigned int, x);
    u += 0x7fffu + ((u >> 16) & 1u);          // round-to-nearest-even
    return (unsigned short)(u >> 16);
}
__device__ inline float bf2f(unsigned short u) {
    return __builtin_bit_cast(float, (unsigned int)u << 16);
}
// pack two f32 -> (bf16(b)<<16)|bf16(a), round-half-up (1 ULP bias negligible)
__device__ inline unsigned pack_bf2(float a, float b) {
    unsigned ua = __builtin_bit_cast(unsigned, a) + 0x8000u;
    unsigned ub = __builtin_bit_cast(unsigned, b) + 0x8000u;
    return __builtin_amdgcn_perm(ub, ua, 0x07060302);
}

// async global->LDS DMA, 16B per lane; HW writes lane i's 16B to lds + 16*i.
__device__ inline void async_ld16(const unsigned short* g, unsigned short* l) {
    __builtin_amdgcn_global_load_lds(
        (const __attribute__((address_space(1))) unsigned int*)(const unsigned int*)g,
        (__attribute__((address_space(3))) unsigned int*)(unsigned int*)l,
        16, 0, 0);
}

// ---------------- Kernel 0: prep — convert X to bf16; transpose W's to bf16 [n][k] ----------------
__global__ __launch_bounds__(256) void prep(
    const float* __restrict__ X, const float* __restrict__ Wqkv,
    const float* __restrict__ Wo,
    unsigned short* __restrict__ Xb, unsigned short* __restrict__ WqkvT,
    unsigned short* __restrict__ WoT)
{
    __shared__ float tile[32][36];
    const int blk = blockIdx.x;
    const int tid = threadIdx.x;
    if (blk < 1024) {
        const int base = blk * 4096 + tid * 16;
        #pragma unroll
        for (int i = 0; i < 4; ++i) {
            float4 v = *(const float4*)(X + base + i * 4);
            ushort4 o;
            o.x = f2bf(v.x); o.y = f2bf(v.y); o.z = f2bf(v.z); o.w = f2bf(v.w);
            *(ushort4*)(Xb + base + i * 4) = o;
        }
        return;
    }
    const float* src; unsigned short* dst; int N, t;
    if (blk < 1792) { src = Wqkv; dst = WqkvT; N = 1536; t = blk - 1024; }
    else            { src = Wo;   dst = WoT;   N = 512;  t = blk - 1792; }
    const int tnx = N / 32;
    const int bx = t % tnx;
    const int by = t / tnx;
    const int row = tid >> 3;
    const int c4  = (tid & 7) * 4;
    *(float4*)&tile[row][c4] = *(const float4*)(src + (size_t)(by * 32 + row) * N + bx * 32 + c4);
    __syncthreads();
    ushort4 o;
    o.x = f2bf(tile[c4 + 0][row]);
    o.y = f2bf(tile[c4 + 1][row]);
    o.z = f2bf(tile[c4 + 2][row]);
    o.w = f2bf(tile[c4 + 3][row]);
    *(ushort4*)(dst + (size_t)(bx * 32 + row) * 512 + by * 32 + c4) = o;
}

// ---------------- Kernel A: QKV projection, bf16 MFMA, BK=64 ----------------
// Q is PRE-SCALED by log2(e) so attention softmax can use raw exp2.
__global__ __launch_bounds__(256) void qkv_mfma(
    const unsigned short* __restrict__ Xb, const unsigned short* __restrict__ WT,
    const float* __restrict__ bias,
    unsigned short* __restrict__ Q, unsigned short* __restrict__ K,
    unsigned short* __restrict__ Vt)
{
    __shared__ unsigned short sA[128 * 64];
    __shared__ unsigned short sB[128 * 64];
    const int tid  = threadIdx.x;
    const int w    = tid >> 6;
    const int lane = tid & 63;
    const int l16  = lane & 15;
    const int quad = lane >> 4;
    const int wm = w >> 1, wn = w & 1;
    const int n0 = blockIdx.x * 128;
    const int m0 = blockIdx.y * 128;

    const unsigned short* gA[4]; const unsigned short* gB[4];
    unsigned short *lA[4], *lB[4];
    #pragma unroll
    for (int j = 0; j < 4; ++j) {
        const int ci = tid + j * 256;
        const int row = ci >> 3;
        const int col = ((ci & 7) ^ (row & 7)) * 8;
        gA[j] = Xb + (size_t)(m0 + row) * 512 + col;
        gB[j] = WT + (size_t)(n0 + row) * 512 + col;
        lA[j] = sA + ci * 8 - lane * 8;
        lB[j] = sB + ci * 8 - lane * 8;
    }

    f32x4 acc[4][4] = {};
    for (int k0 = 0; k0 < 512; k0 += 64) {
        __syncthreads();
        #pragma unroll
        for (int j = 0; j < 4; ++j) {
            async_ld16(gA[j] + k0, lA[j]);
            async_ld16(gB[j] + k0, lB[j]);
        }
        __syncthreads();
        bf16x8 a[4][2], bfr[4][2];
        #pragma unroll
        for (int mi = 0; mi < 4; ++mi) {
            const int row = wm * 64 + mi * 16 + l16;
            a[mi][0] = *(const bf16x8*)&sA[row * 64 + ((quad       ^ (row & 7)) * 8)];
            a[mi][1] = *(const bf16x8*)&sA[row * 64 + (((4 + quad) ^ (row & 7)) * 8)];
        }
        #pragma unroll
        for (int ni = 0; ni < 4; ++ni) {
            const int row = wn * 64 + ni * 16 + l16;
            bfr[ni][0] = *(const bf16x8*)&sB[row * 64 + ((quad       ^ (row & 7)) * 8)];
            bfr[ni][1] = *(const bf16x8*)&sB[row * 64 + (((4 + quad) ^ (row & 7)) * 8)];
        }
        #pragma unroll
        for (int mi = 0; mi < 4; ++mi)
            #pragma unroll
            for (int ni = 0; ni < 4; ++ni) {
                acc[mi][ni] = __builtin_amdgcn_mfma_f32_16x16x32_bf16(a[mi][0], bfr[ni][0], acc[mi][ni], 0, 0, 0);
                acc[mi][ni] = __builtin_amdgcn_mfma_f32_16x16x32_bf16(a[mi][1], bfr[ni][1], acc[mi][ni], 0, 0, 0);
            }
    }

    const int which = n0 >> 9;
    const int h = ((n0 & 511) >> 6) + wn;
    const int b = m0 >> 11;
    const int sbase = (m0 & 2047) + wm * 64;
    float bv[4];
    #pragma unroll
    for (int ni = 0; ni < 4; ++ni) bv[ni] = bias[n0 + wn * 64 + ni * 16 + l16];
    if (which == 2) {
        #pragma unroll
        for (int ni = 0; ni < 4; ++ni) {
            const int dh = ni * 16 + l16;
            unsigned short* vp = Vt + ((size_t)(b * H_NUM + h) * DH + dh) * S_LEN;
            #pragma unroll
            for (int mi = 0; mi < 4; ++mi) {
                const int s0 = sbase + mi * 16 + quad * 4;
                ushort4 o;
                o.x = f2bf(acc[mi][ni][0] + bv[ni]);
                o.y = f2bf(acc[mi][ni][1] + bv[ni]);
                o.z = f2bf(acc[mi][ni][2] + bv[ni]);
                o.w = f2bf(acc[mi][ni][3] + bv[ni]);
                *(ushort4*)(vp + s0) = o;
            }
        }
    } else {
        const float qs = (which == 0) ? LOG2E : 1.0f;   // Q pre-scaled for exp2 softmax
        unsigned short* dst = (which == 0) ? Q : K;
        dst += (size_t)(b * H_NUM + h) * S_LEN * DH;
        #pragma unroll
        for (int mi = 0; mi < 4; ++mi)
            #pragma unroll
            for (int r = 0; r < 4; ++r) {
                const int s = sbase + mi * 16 + quad * 4 + r;
                #pragma unroll
                for (int ni = 0; ni < 4; ++ni)
                    dst[(size_t)s * DH + ni * 16 + l16] = f2bf((acc[mi][ni][r] + bv[ni]) * qs);
            }
    }
}

// ---------------- Kernel B: flash attention — permuted-K register-direct P ----------------
// Grid (16 qt, 32 bh). Block: 128 Q rows, all 32 K-tiles; output written normalized.
// 4 waves = 2 qg x 2 kg. Wave (qg,kg): q-rows qg*64 + t*16 + [0,16), kpos kg*32+[0,32).
// S^T QK with PERMUTED K rows: c0's m-block loads kpos π(m)=8(m>>2)+(m&3), c1 loads π+4.
// Then lane (l16,quad) exits QK holding kpos {8q..8q+7} for qrow=l16 — exactly the
// PV A-fragment layout. P: C-regs -> pack_bf2 -> PV operand. No LDS, no shuffles.
// Cross-kg (O, l) reduced once via LDS at the epilogue (additive no-max softmax).
__global__ __launch_bounds__(256, 2) void attn_mfma(
    const unsigned short* __restrict__ Q, const unsigned short* __restrict__ K,
    const unsigned short* __restrict__ Vt, const int* __restrict__ mask,
    unsigned short* __restrict__ attb)
{
    __shared__ __align__(16) char smem[36864];
    unsigned short* sK  = (unsigned short*)smem;            // [2][4096] swizzled
    unsigned short* sVt = (unsigned short*)(smem + 16384);  // [2][4096] swizzled
    float* smbt = (float*)(smem + 32768);                   // [2][64]
    // epilogue aliases (after post-loop barrier):
    float* red  = (float*)smem;                             // [128][68]
    float* lred = (float*)(smem + 34816);                   // [2][128]

    const int tid  = threadIdx.x;
    const int w    = tid >> 6;
    const int lane = tid & 63;
    const int l16  = lane & 15;
    const int quad = lane >> 4;
    const int qg = w >> 1;           // q-group: rows qg*64..+63
    const int kg = w & 1;            // k-group: kpos kg*32..+31 of each 64-tile
    const int qt = blockIdx.x;       // 0..15
    const int bh = blockIdx.y;       // 0..31
    const int b  = bh >> 3;
    const int h  = bh & 7;
    const size_t kbase = (size_t)bh * S_LEN * DH;
    const size_t vbase = (size_t)bh * DH * S_LEN;

    // Q fragments direct from global (B-operand: n=qrow=l16, k=quad*8+j)
    bf16x8 qf[4][2];
    {
        const unsigned short* qp = Q + kbase + (size_t)(qt * 128 + qg * 64 + l16) * DH + quad * 8;
        #pragma unroll
        for (int t = 0; t < 4; ++t) {
            qf[t][0] = *(const bf16x8*)(qp + t * 16 * DH);
            qf[t][1] = *(const bf16x8*)(qp + t * 16 * DH + 32);
        }
    }

    // DMA chunk geometry (512 chunks per 8KB tile; 8 chunks/row, XOR row&7)
    const int ci0 = w * 128 + lane;
    const int ci1 = ci0 + 64;
    const int r0_ = ci0 >> 3, c0_ = ((ci0 & 7) ^ (r0_ & 7)) * 8;
    const int r1_ = ci1 >> 3, c1_ = ((ci1 & 7) ^ (r1_ & 7)) * 8;
    const int kOff0 = r0_ * 64 + c0_;
    const int kOff1 = r1_ * 64 + c1_;
    const int vOff0 = r0_ * S_LEN + c0_;
    const int vOff1 = r1_ * S_LEN + c1_;
    const int lds0 = ci0 * 8 - lane * 8;
    const int lds1 = ci1 * 8 - lane * 8;

    f32x4 O[4][4] = {};      // [t][db]
    float lacc[4] = {};      // per-lane l partial (qrow = l16 of tile t)

    // permuted K row (π for c0; c1 adds 4): kpos = 8*(l16>>2) + (l16&3)
    const int prow = (l16 >> 2) * 8 + (l16 & 3);

    // prologue: prefetch tile 0 into buffer 0
    {
        const unsigned short* gK = K  + kbase;
        const unsigned short* gV = Vt + vbase;
        async_ld16(gK + kOff0, sK + lds0);
        async_ld16(gK + kOff1, sK + lds1);
        async_ld16(gV + vOff0, sVt + lds0);
        async_ld16(gV + vOff1, sVt + lds1);
        if (tid < 64) smbt[tid] = mask[b * S_LEN + tid] ? 0.f : -1e30f;
    }

    for (int kt = 0; kt < 32; ++kt) {
        const int cur = kt & 1, nxt = cur ^ 1;
        __syncthreads();   // drains DMA(kt), orders smbt, fences buffer reuse
        if (kt + 1 < 32) {
            const unsigned short* gK = K  + kbase + (size_t)(kt + 1) * 64 * DH;
            const unsigned short* gV = Vt + vbase + (kt + 1) * 64;
            async_ld16(gK + kOff0, sK + nxt * 4096 + lds0);
            async_ld16(gK + kOff1, sK + nxt * 4096 + lds1);
            async_ld16(gV + vOff0, sVt + nxt * 4096 + lds0);
            async_ld16(gV + vOff1, sVt + nxt * 4096 + lds1);
            if (tid < 64) smbt[nxt * 64 + tid] = mask[b * S_LEN + (kt + 1) * 64 + tid] ? 0.f : -1e30f;
        }
        const unsigned short* sKc = sK  + cur * 4096;
        const unsigned short* sVc = sVt + cur * 4096;

        // K fragments (A-operand, m=kpos) with π permutation
        bf16x8 kb[2][2];
        #pragma unroll
        for (int kpb = 0; kpb < 2; ++kpb) {
            const int row = kg * 32 + prow + kpb * 4;   // kpb=0 -> c0 rows, 1 -> c1 rows
            const int x = row & 7;
            kb[kpb][0] = *(const bf16x8*)&sKc[row * 64 + ((quad       ^ x) * 8)];
            kb[kpb][1] = *(const bf16x8*)&sKc[row * 64 + (((4 + quad) ^ x) * 8)];
        }
        // mask bias follows the permutation: c0 reg r <-> kpos 8q+r, c1 <-> 8q+4+r
        float4 mb0 = *(const float4*)&smbt[cur * 64 + kg * 32 + quad * 8];
        float4 mb1 = *(const float4*)&smbt[cur * 64 + kg * 32 + quad * 8 + 4];

        // V fragments (B-operand, n=dh, k = this wave's 32 kpos)
        bf16x8 vb[4];
        #pragma unroll
        for (int db = 0; db < 4; ++db) {
            const int row = db * 16 + l16;
            const int x = row & 7;
            vb[db] = *(const bf16x8*)&sVc[row * 64 + (((kg * 4 + quad) ^ x) * 8)];
        }

        #pragma unroll
        for (int t = 0; t < 4; ++t) {
            f32x4 c0 = {0,0,0,0}, c1 = {0,0,0,0};
            c0 = __builtin_amdgcn_mfma_f32_16x16x32_bf16(kb[0][0], qf[t][0], c0, 0, 0, 0);
            c0 = __builtin_amdgcn_mfma_f32_16x16x32_bf16(kb[0][1], qf[t][1], c0, 0, 0, 0);
            c1 = __builtin_amdgcn_mfma_f32_16x16x32_bf16(kb[1][0], qf[t][0], c1, 0, 0, 0);
            c1 = __builtin_amdgcn_mfma_f32_16x16x32_bf16(kb[1][1], qf[t][1], c1, 0, 0, 0);

            // p = exp2(score + maskbias); lane holds kpos 8q+0..7 for qrow=l16
            const float p0 = __builtin_amdgcn_exp2f(c0[0] + mb0.x);
            const float p1 = __builtin_amdgcn_exp2f(c0[1] + mb0.y);
            const float p2 = __builtin_amdgcn_exp2f(c0[2] + mb0.z);
            const float p3 = __builtin_amdgcn_exp2f(c0[3] + mb0.w);
            const float p4 = __builtin_amdgcn_exp2f(c1[0] + mb1.x);
            const float p5 = __builtin_amdgcn_exp2f(c1[1] + mb1.y);
            const float p6 = __builtin_amdgcn_exp2f(c1[2] + mb1.z);
            const float p7 = __builtin_amdgcn_exp2f(c1[3] + mb1.w);
            lacc[t] += ((p0 + p1) + (p2 + p3)) + ((p4 + p5) + (p6 + p7));

            uint4 paw;
            paw.x = pack_bf2(p0, p1);   // kpos 8q+0,1
            paw.y = pack_bf2(p2, p3);   // kpos 8q+2,3
            paw.z = pack_bf2(p4, p5);   // kpos 8q+4,5
            paw.w = pack_bf2(p6, p7);   // kpos 8q+6,7
            const bf16x8 pa = __builtin_bit_cast(bf16x8, paw);
            #pragma unroll
            for (int db = 0; db < 4; ++db)
                O[t][db] = __builtin_amdgcn_mfma_f32_16x16x32_bf16(pa, vb[db], O[t][db], 0, 0, 0);
        }
    }

    // ---- epilogue: reduce l over quads; cross-kg reduce via LDS; normalized write ----
    #pragma unroll
    for (int t = 0; t < 4; ++t) {
        lacc[t] += __shfl_xor(lacc[t], 16, 64);
        lacc[t] += __shfl_xor(lacc[t], 32, 64);   // all lanes: l(qrow=l16) of tile t
    }
    __syncthreads();                               // main-loop LDS dead; alias as red/lred
    if (quad == 0) {
        #pragma unroll
        for (int t = 0; t < 4; ++t)
            lred[kg * 128 + qg * 64 + t * 16 + l16] = lacc[t];
    }
    if (kg == 1) {
        #pragma unroll
        for (int t = 0; t < 4; ++t)
            #pragma unroll
            for (int db = 0; db < 4; ++db)
                #pragma unroll
                for (int r = 0; r < 4; ++r)
                    red[(size_t)(qg * 64 + t * 16 + quad * 4 + r) * 68 + db * 16 + l16] = O[t][db][r];
    }
    __syncthreads();
    if (kg == 0) {
        #pragma unroll
        for (int t = 0; t < 4; ++t) {
            #pragma unroll
            for (int r = 0; r < 4; ++r) {
                const int lrow = qg * 64 + t * 16 + quad * 4 + r;
                const float inv = 1.0f / (lred[lrow] + lred[128 + lrow]);
                const size_t grow = (size_t)b * S_LEN + qt * 128 + lrow;
                unsigned short* op = attb + grow * 512 + h * DH + l16;
                op[0]  = f2bf((O[t][0][r] + red[(size_t)lrow * 68 +  0 + l16]) * inv);
                op[16] = f2bf((O[t][1][r] + red[(size_t)lrow * 68 + 16 + l16]) * inv);
                op[32] = f2bf((O[t][2][r] + red[(size_t)lrow * 68 + 32 + l16]) * inv);
                op[48] = f2bf((O[t][3][r] + red[(size_t)lrow * 68 + 48 + l16]) * inv);
            }
        }
    }
}

// ---------------- Kernel C: out-proj GEMM, bf16 MFMA, BK=64 ----------------
__global__ __launch_bounds__(256) void proj_mfma(
    const unsigned short* __restrict__ attb, const unsigned short* __restrict__ WoT,
    const float* __restrict__ bo, float* __restrict__ xbuf)
{
    __shared__ unsigned short sA[128 * 64];
    __shared__ unsigned short sB[64 * 64];
    const int tid  = threadIdx.x;
    const int w    = tid >> 6;
    const int lane = tid & 63;
    const int l16  = lane & 15;
    const int quad = lane >> 4;
    const int wm = w >> 1, wn = w & 1;
    const int n0 = blockIdx.x * 64;
    const int m0 = blockIdx.y * 128;

    const unsigned short* gA[4]; unsigned short* lA[4];
    const unsigned short* gB[2]; unsigned short* lB[2];
    #pragma unroll
    for (int j = 0; j < 4; ++j) {
        const int ci = tid + j * 256;
        const int row = ci >> 3;
        const int col = ((ci & 7) ^ (row & 7)) * 8;
        gA[j] = attb + (size_t)(m0 + row) * 512 + col;
        lA[j] = sA + ci * 8 - lane * 8;
    }
    #pragma unroll
    for (int j = 0; j < 2; ++j) {
        const int ci = tid + j * 256;
        const int row = ci >> 3;
        const int col = ((ci & 7) ^ (row & 7)) * 8;
        gB[j] = WoT + (size_t)(n0 + row) * 512 + col;
        lB[j] = sB + ci * 8 - lane * 8;
    }

    f32x4 acc[4][2] = {};
    for (int k0 = 0; k0 < 512; k0 += 64) {
        __syncthreads();
        #pragma unroll
        for (int j = 0; j < 4; ++j) async_ld16(gA[j] + k0, lA[j]);
        #pragma unroll
        for (int j = 0; j < 2; ++j) async_ld16(gB[j] + k0, lB[j]);
        __syncthreads();
        bf16x8 a[4][2], bfr[2][2];
        #pragma unroll
        for (int mi = 0; mi < 4; ++mi) {
            const int row = wm * 64 + mi * 16 + l16;
            a[mi][0] = *(const bf16x8*)&sA[row * 64 + ((quad       ^ (row & 7)) * 8)];
            a[mi][1] = *(const bf16x8*)&sA[row * 64 + (((4 + quad) ^ (row & 7)) * 8)];
        }
        #pragma unroll
        for (int ni = 0; ni < 2; ++ni) {
            const int row = wn * 32 + ni * 16 + l16;
            bfr[ni][0] = *(const bf16x8*)&sB[row * 64 + ((quad       ^ (row & 7)) * 8)];
            bfr[ni][1] = *(const bf16x8*)&sB[row * 64 + (((4 + quad) ^ (row & 7)) * 8)];
        }
        #pragma unroll
        for (int mi = 0; mi < 4; ++mi)
            #pragma unroll
            for (int ni = 0; ni < 2; ++ni) {
                acc[mi][ni] = __builtin_amdgcn_mfma_f32_16x16x32_bf16(a[mi][0], bfr[ni][0], acc[mi][ni], 0, 0, 0);
                acc[mi][ni] = __builtin_amdgcn_mfma_f32_16x16x32_bf16(a[mi][1], bfr[ni][1], acc[mi][ni], 0, 0, 0);
            }
    }

    #pragma unroll
    for (int ni = 0; ni < 2; ++ni) {
        const int n = n0 + wn * 32 + ni * 16 + l16;
        const float bv = bo[n];
        #pragma unroll
        for (int mi = 0; mi < 4; ++mi) {
            #pragma unroll
            for (int r = 0; r < 4; ++r) {
                const int m = m0 + wm * 64 + mi * 16 + quad * 4 + r;
                const float resid = bf2f(attb[(size_t)m * 512 + n]);
                xbuf[(size_t)m * 512 + n] = acc[mi][ni][r] + bv + resid;
            }
        }
    }
}

// ---------------- Kernel D: LayerNorm ----------------
__global__ __launch_bounds__(256) void ln_kernel(
    const float* __restrict__ xbuf, const float* __restrict__ gamma,
    const float* __restrict__ beta, float* __restrict__ out)
{
    const int tid = threadIdx.x;
    const int w = tid >> 6, lane = tid & 63;
    const size_t row = (size_t)blockIdx.x * 4 + w;
    const float* xp = xbuf + row * 512 + lane * 8;
    float4 v0 = *(const float4*)xp;
    float4 v1 = *(const float4*)(xp + 4);
    float s  = v0.x + v0.y + v0.z + v0.w + v1.x + v1.y + v1.z + v1.w;
    float sq = v0.x*v0.x + v0.y*v0.y + v0.z*v0.z + v0.w*v0.w
             + v1.x*v1.x + v1.y*v1.y + v1.z*v1.z + v1.w*v1.w;
    #pragma unroll
    for (int off = 1; off < 64; off <<= 1) {
        s  += __shfl_xor(s, off, 64);
        sq += __shfl_xor(sq, off, 64);
    }
    const float mu = s * (1.0f / 512.0f);
    const float var = sq * (1.0f / 512.0f) - mu * mu;
    const float rs = rsqrtf(var + 1e-5f);
    float4 g0 = *(const float4*)(gamma + lane * 8);
    float4 g1 = *(const float4*)(gamma + lane * 8 + 4);
    float4 b0 = *(const float4*)(beta + lane * 8);
    float4 b1 = *(const float4*)(beta + lane * 8 + 4);
    float4 o0, o1;
    o0.x = (v0.x - mu) * rs * g0.x + b0.x;
    o0.y = (v0.y - mu) * rs * g0.y + b0.y;
    o0.z = (v0.z - mu) * rs * g0.z + b0.z;
    o0.w = (v0.w - mu) * rs * g0.w + b0.w;
    o1.x = (v1.x - mu) * rs * g1.x + b1.x;
    o1.y = (v1.y - mu) * rs * g1.y + b1.y;
    o1.z = (v1.z - mu) * rs * g1.z + b1.z;
    o1.w = (v1.w - mu) * rs * g1.w + b1.w;
    float* op = out + row * 512 + lane * 8;
    *(float4*)op = o0;
    *(float4*)(op + 4) = o1;
}

extern "C" void kernel_launch(void* const* d_in, const int* in_sizes, int n_in,
                              void* d_out, int out_size, void* d_ws, size_t ws_size,
                              hipStream_t stream)
{
    (void)in_sizes; (void)n_in; (void)out_size; (void)ws_size;
    const float* X    = (const float*)d_in[0];
    const int*   mask = (const int*)d_in[1];
    const float* Wqkv = (const float*)d_in[2];
    const float* bqkv = (const float*)d_in[3];
    const float* Wo   = (const float*)d_in[4];
    const float* bo   = (const float*)d_in[5];
    const float* gamma= (const float*)d_in[6];
    const float* beta = (const float*)d_in[7];
    float* out = (float*)d_out;

    const size_t NE = (size_t)4 * S_LEN * D_MODEL;      // 4,194,304
    unsigned short* ws16 = (unsigned short*)d_ws;
    unsigned short* Xb     = ws16;                       // NE
    unsigned short* WqkvT  = Xb + NE;                    // 786432
    unsigned short* WoT    = WqkvT + 786432;             // 262144
    unsigned short* Q      = WoT + 262144;               // NE
    unsigned short* K      = Q + NE;                     // NE
    unsigned short* Vt     = K + NE;                     // NE
    unsigned short* attb   = Vt + NE;                    // NE
    float* xbuf = (float*)(attb + NE);                   // NE f32

    prep<<<dim3(2048), 256, 0, stream>>>(X, Wqkv, Wo, Xb, WqkvT, WoT);
    qkv_mfma<<<dim3(12, 64), 256, 0, stream>>>(Xb, WqkvT, bqkv, Q, K, Vt);
    attn_mfma<<<dim3(16, 32), 256, 0, stream>>>(Q, K, Vt, mask, attb);
    proj_mfma<<<dim3(8, 64), 256, 0, stream>>>(attb, WoT, bo, xbuf);
    ln_kernel<<<dim3(2048), 256, 0, stream>>>(xbuf, gamma, beta, out);
}